// Round 15
// baseline (125.853 us; speedup 1.0000x reference)
//
#include <hip/hip_runtime.h>
#include <hip/hip_bf16.h>

typedef __attribute__((ext_vector_type(8))) short short8;
typedef __attribute__((ext_vector_type(4))) short short4b;
typedef __attribute__((ext_vector_type(4))) float f32x4;
typedef __attribute__((ext_vector_type(16))) float f32x16;
typedef __attribute__((ext_vector_type(4))) unsigned u32x4;

static constexpr int Bb = 2, Tt = 2048, Cc = 1024, Hh = 16;
static constexpr int BT = Bb * Tt;     // 4096
static constexpr int N1 = 3 * Cc;      // 3072
static constexpr float QS = 0.125f * 1.44269504f;  // 1/sqrt(64) * log2(e)

__device__ __forceinline__ unsigned short f2b(float f) {
  union { float f; unsigned u; } v; v.f = f;
  unsigned r = v.u + 0x7fffu + ((v.u >> 16) & 1u);
  return (unsigned short)(r >> 16);
}
__device__ __forceinline__ float b2f(short s) {
  union { unsigned u; float f; } v; v.u = ((unsigned)(unsigned short)s) << 16;
  return v.f;
}

// ---------------- cast f32 -> bf16, 8 elems/thread ----------------
__global__ __launch_bounds__(256) void k_cast(const float* __restrict__ in,
                                              unsigned short* __restrict__ out, int n) {
  int i = (blockIdx.x * 256 + threadIdx.x) * 8;
  if (i >= n) return;
  float4 a = *reinterpret_cast<const float4*>(in + i);
  float4 b = *reinterpret_cast<const float4*>(in + i + 4);
  short8 o;
  o[0] = f2b(a.x); o[1] = f2b(a.y); o[2] = f2b(a.z); o[3] = f2b(a.w);
  o[4] = f2b(b.x); o[5] = f2b(b.y); o[6] = f2b(b.z); o[7] = f2b(b.w);
  *reinterpret_cast<short8*>(out + i) = o;
}

// ------------- transpose + cast: in R x Ccol f32 -> out Ccol x R bf16 -------------
__global__ __launch_bounds__(256) void k_tcast(const float* __restrict__ in,
                                               unsigned short* __restrict__ out,
                                               int R, int Ccol) {
  __shared__ float tile[32][33];
  int cb = blockIdx.x * 32, rb = blockIdx.y * 32;
  int tx = threadIdx.x & 31, ty = threadIdx.x >> 5;  // ty 0..7
  for (int i = 0; i < 32; i += 8)
    tile[ty + i][tx] = in[(size_t)(rb + ty + i) * Ccol + cb + tx];
  __syncthreads();
  for (int i = 0; i < 32; i += 8)
    out[(size_t)(cb + ty + i) * R + rb + tx] = f2b(tile[tx][ty + i]);
}

// ---------------- 8-wave phase-split GEMM (R11-proven) ----------------------------
template <int BM, int NF, int EPI>
__global__ __launch_bounds__(512, 2)
void k_gemm8(const unsigned short* __restrict__ A, const unsigned short* __restrict__ Bt,
             const float* __restrict__ bias, void* __restrict__ Cout,
             const float* __restrict__ rope, unsigned short* __restrict__ Qs,
             unsigned short* __restrict__ Ks, unsigned short* __restrict__ Vt,
             int M, int N, int K) {
  constexpr int BN = NF * 64;
  constexpr int MF = BM / 32;
  constexpr int AI = BM / 64;
  constexpr int ASZ = BM * 64;
  constexpr int BSZ = BN * 64;
  constexpr int STRIDE = ASZ + BSZ;
  extern __shared__ unsigned short lds[];
  const int tid = threadIdx.x, lane = tid & 63, w = tid >> 6;
  const int wm = w >> 2, wn = w & 3;
  const int l15 = lane & 15, l4 = lane >> 4;
  int nbx = gridDim.x;
  int lin = blockIdx.y * nbx + blockIdx.x;
  int cpx = (nbx * gridDim.y) >> 3;
  lin = (lin & 7) * cpx + (lin >> 3);
  const int mb = lin / nbx, nb = lin % nbx;
  const size_t arow0 = (size_t)mb * BM;
  const size_t brow0 = (size_t)nb * BN;

  const int srow = lane >> 3;
  const int scol = (((lane & 7) * 16) ^ (srow << 4)) >> 1;
  auto stage = [&](int buf, int k0) {
    unsigned short* Ab = lds + buf * STRIDE;
    unsigned short* Bb = Ab + ASZ;
#pragma unroll
    for (int i = 0; i < AI; i++) {
      int c = w + 8 * i;
      const unsigned short* g = A + (arow0 + c * 8 + srow) * (size_t)K + k0 + scol;
      __builtin_amdgcn_global_load_lds((const __attribute__((address_space(1))) void*)g,
          (__attribute__((address_space(3))) void*)(Ab + c * 512), 16, 0, 0);
    }
#pragma unroll
    for (int i = 0; i < NF; i++) {
      int c = w + 8 * i;
      const unsigned short* g = Bt + (brow0 + c * 8 + srow) * (size_t)K + k0 + scol;
      __builtin_amdgcn_global_load_lds((const __attribute__((address_space(1))) void*)g,
          (__attribute__((address_space(3))) void*)(Bb + c * 512), 16, 0, 0);
    }
  };

  f32x4 acc[MF][NF] = {};
  const int NK = K >> 6;

  stage(0, 0);
  asm volatile("s_waitcnt vmcnt(0)" ::: "memory");
  asm volatile("s_barrier" ::: "memory");

  for (int kt = 0; kt < NK; kt++) {
    int buf = kt & 1;
    if (kt + 1 < NK) stage(buf ^ 1, (kt + 1) << 6);
    const unsigned short* Ab = lds + buf * STRIDE;
    const unsigned short* Bb = Ab + ASZ;
    short8 af[MF][2];
#pragma unroll
    for (int p = 0; p < NF; p++) {
      if (p == 0) {
#pragma unroll
        for (int m = 0; m < MF; m++) {
          int ra = wm * (BM / 2) + m * 16 + l15;
#pragma unroll
          for (int kk = 0; kk < 2; kk++) {
            int cb = (kk * 64 + l4 * 16) ^ ((ra & 7) << 4);
            af[m][kk] = *reinterpret_cast<const short8*>(Ab + ra * 64 + (cb >> 1));
          }
        }
      }
      short8 bfr[2];
      int rb = wn * (NF * 16) + p * 16 + l15;
#pragma unroll
      for (int kk = 0; kk < 2; kk++) {
        int cb = (kk * 64 + l4 * 16) ^ ((rb & 7) << 4);
        bfr[kk] = *reinterpret_cast<const short8*>(Bb + rb * 64 + (cb >> 1));
      }
      asm volatile("s_barrier" ::: "memory");
      asm volatile("s_waitcnt lgkmcnt(0)" ::: "memory");
      __builtin_amdgcn_sched_barrier(0);
      __builtin_amdgcn_s_setprio(1);
#pragma unroll
      for (int m = 0; m < MF; m++) {
        acc[m][p] = __builtin_amdgcn_mfma_f32_16x16x32_bf16(af[m][0], bfr[0], acc[m][p], 0, 0, 0);
        acc[m][p] = __builtin_amdgcn_mfma_f32_16x16x32_bf16(af[m][1], bfr[1], acc[m][p], 0, 0, 0);
      }
      __builtin_amdgcn_s_setprio(0);
      if (p == NF - 1)
        asm volatile("s_waitcnt vmcnt(0)" ::: "memory");
      asm volatile("s_barrier" ::: "memory");
    }
  }

#pragma unroll
  for (int m = 0; m < MF; m++) {
#pragma unroll
    for (int n = 0; n < NF; n++) {
      int ccol0 = nb * BN + wn * (NF * 16) + n * 16;
      float bv = bias[ccol0 + l15];
      int r0 = mb * BM + wm * (BM / 2) + m * 16 + l4 * 4;
      if (EPI == 0) {
#pragma unroll
        for (int j = 0; j < 4; j++)
          ((float*)Cout)[(size_t)(r0 + j) * N + ccol0 + l15] = acc[m][n][j] + bv;
      } else {
        int cls = ccol0 >> 10;               // 0=q 1=k 2=v
        int h = (ccol0 >> 6) & 15;
        int d = (ccol0 & 63) + l15;
        int bq = r0 >> 11;
        int t0 = r0 & 2047;
        size_t bh = (size_t)bq * 16 + h;
        if (cls == 2) {
          short4b o;
#pragma unroll
          for (int j = 0; j < 4; j++) o[j] = (short)f2b(acc[m][n][j] + bv);
          *reinterpret_cast<short4b*>(Vt + (bh * 64 + d) * Tt + t0) = o;
        } else {
          unsigned short* dst = (cls == 0) ? Qs : Ks;
          int jj = d >> 1;
          int odd = d & 1;
#pragma unroll
          for (int j = 0; j < 4; j++) {
            float v = acc[m][n][j] + bv;
            float part = __shfl_xor(v, 1);
            float2 sc = *reinterpret_cast<const float2*>(
                rope + (size_t)(t0 + j) * 128 + jj * 4 + 2);   // (sin, cos)
            float x = odd ? part : v;
            float y = odd ? v : part;
            float rot = odd ? (x * sc.x + y * sc.y)
                            : (x * sc.y - y * sc.x);
            if (cls == 0) rot *= QS;
            dst[(bh * Tt + (t0 + j)) * 64 + d] = f2b(rot);
          }
        }
      }
    }
  }
}

__device__ __forceinline__ float tmax16(const f32x16& v) {
  float a0 = fmaxf(v[0], v[1]),   a1 = fmaxf(v[2], v[3]);
  float a2 = fmaxf(v[4], v[5]),   a3 = fmaxf(v[6], v[7]);
  float a4 = fmaxf(v[8], v[9]),   a5 = fmaxf(v[10], v[11]);
  float a6 = fmaxf(v[12], v[13]), a7 = fmaxf(v[14], v[15]);
  float b0 = fmaxf(a0, a1), b1 = fmaxf(a2, a3), b2 = fmaxf(a4, a5), b3 = fmaxf(a6, a7);
  return fmaxf(fmaxf(b0, b1), fmaxf(b2, b3));
}

// ------------- attention pass-1 tile (R11-proven, inline addressing) -------------
__device__ __forceinline__ void attn_tile64(
    const unsigned short* Kl, const unsigned short* Vl,
    int w, int l31, int hi, const short8 qf[4],
    float& m_run, float& l_run, f32x16 oacc[2], int grelBase) {
  f32x16 sc[2];
  bool act[2];
#pragma unroll
  for (int kt = 0; kt < 2; kt++) {
    int grel = grelBase + kt;
    act[kt] = (grel <= w);
    if (!act[kt]) continue;
    f32x16 acc = {};
    int rk = kt * 32 + l31;
    int sw = (rk & 7) << 4;
    const unsigned short* krow = Kl + rk * 64;
    short8 kf[4];
#pragma unroll
    for (int kk = 0; kk < 4; kk++)
      kf[kk] = *reinterpret_cast<const short8*>(krow + (((kk * 32 + hi * 16) ^ sw) >> 1));
    __builtin_amdgcn_s_setprio(1);
#pragma unroll
    for (int kk = 0; kk < 4; kk++)
      acc = __builtin_amdgcn_mfma_f32_32x32x16_bf16(kf[kk], qf[kk], acc, 0, 0, 0);
    __builtin_amdgcn_s_setprio(0);
    if (grel == w) {
#pragma unroll
      for (int r = 0; r < 16; r++) {
        int e = (r & 3) + 8 * (r >> 2) + 4 * hi;
        if (e > l31) acc[r] = -1e30f;
      }
    }
    sc[kt] = acc;
  }
  float km0 = act[0] ? tmax16(sc[0]) : -1e30f;
  float km1 = act[1] ? tmax16(sc[1]) : -1e30f;
  float mx = fmaxf(km0, km1);
  mx = fmaxf(mx, __shfl_xor(mx, 32));

  float fsc = 1.f;
  if (!__all(mx <= m_run + 8.f)) {
    float nm = fmaxf(m_run, mx);
    fsc = __builtin_amdgcn_exp2f(m_run - nm);
    m_run = nm;
#pragma unroll
    for (int dt = 0; dt < 2; dt++)
#pragma unroll
      for (int r = 0; r < 16; r++) oacc[dt][r] *= fsc;
  }

  float kps[2] = {0.f, 0.f};
#pragma unroll
  for (int kt = 0; kt < 2; kt++) {
    if (!act[kt]) continue;
    float p[16];
#pragma unroll
    for (int r = 0; r < 16; r++) p[r] = __builtin_amdgcn_exp2f(sc[kt][r] - m_run);
    float s0 = (p[0] + p[1]) + (p[2] + p[3]);
    float s1 = (p[4] + p[5]) + (p[6] + p[7]);
    float s2 = (p[8] + p[9]) + (p[10] + p[11]);
    float s3 = (p[12] + p[13]) + (p[14] + p[15]);
    kps[kt] = (s0 + s1) + (s2 + s3);
    unsigned P[8];
#pragma unroll
    for (int i = 0; i < 8; i++)
      asm("v_cvt_pk_bf16_f32 %0, %1, %2" : "=v"(P[i]) : "v"(p[2 * i]), "v"(p[2 * i + 1]));
    unsigned Y0 = (unsigned)__shfl_xor((int)(hi ? P[0] : P[2]), 32);
    unsigned Y1 = (unsigned)__shfl_xor((int)(hi ? P[1] : P[3]), 32);
    unsigned Y2 = (unsigned)__shfl_xor((int)(hi ? P[4] : P[6]), 32);
    unsigned Y3 = (unsigned)__shfl_xor((int)(hi ? P[5] : P[7]), 32);
    u32x4 c0 = hi ? u32x4{Y0, Y1, P[2], P[3]} : u32x4{P[0], P[1], Y0, Y1};
    u32x4 c1 = hi ? u32x4{Y2, Y3, P[6], P[7]} : u32x4{P[4], P[5], Y2, Y3};
    short8 pf0 = __builtin_bit_cast(short8, c0);
    short8 pf1 = __builtin_bit_cast(short8, c1);
#pragma unroll
    for (int dt = 0; dt < 2; dt++) {
      int d = dt * 32 + l31;
      int sv = (d & 7) << 4;
      const unsigned short* vrow = Vl + d * 64;
      short8 vf0 = *reinterpret_cast<const short8*>(vrow + (((kt * 64 + hi * 16) ^ sv) >> 1));
      short8 vf1 = *reinterpret_cast<const short8*>(vrow + (((kt * 64 + 32 + hi * 16) ^ sv) >> 1));
      __builtin_amdgcn_s_setprio(1);
      oacc[dt] = __builtin_amdgcn_mfma_f32_32x32x16_bf16(vf0, pf0, oacc[dt], 0, 0, 0);
      oacc[dt] = __builtin_amdgcn_mfma_f32_32x32x16_bf16(vf1, pf1, oacc[dt], 0, 0, 0);
      __builtin_amdgcn_s_setprio(0);
    }
  }
  float psum = kps[0] + kps[1];
  psum += __shfl_xor(psum, 32);
  l_run = l_run * fsc + psum;
}

// ------------- flash attention pass 1: R11 body + persistent work-stealing -------
// 512 persistent blocks; items 0..1023 in R11's qb-descending order via global
// atomic counter. Any block->CU assignment yields near-balanced makespan.
__global__ __launch_bounds__(256)
void k_attn1(const unsigned short* __restrict__ Qs, const unsigned short* __restrict__ Ks,
             const unsigned short* __restrict__ Vt, unsigned short* __restrict__ Opart,
             float* __restrict__ ml, int* __restrict__ ctr) {
  __shared__ unsigned short lds[16384];  // 32KB: 2 slots x (K 4096 + V 4096 shorts)
  __shared__ int s_item;
  int tid = threadIdx.x, lane = tid & 63, w = tid >> 6;
  int l31 = lane & 31, hi = lane >> 5;

  for (;;) {
    if (tid == 0) s_item = atomicAdd(ctr, 1);
    __syncthreads();                     // broadcasts s_item; fences prior LDS use
    int sid = s_item;
    if (sid >= 1024) break;

    int qb = 15 - (sid >> 6);
    int c = (sid >> 5) & 1;
    int bh = sid & 31;
    int qw0 = qb * 128 + w * 32;
    const unsigned short* Qb = Qs + (size_t)bh * Tt * 64;
    const unsigned short* Kb = Ks + (size_t)bh * Tt * 64;
    const unsigned short* Vb = Vt + (size_t)bh * 64 * Tt;

    const int NT = 2 * qb + 2, half = NT >> 1;
    const int t0 = c ? half : 0, t1 = c ? NT : half;

    auto stage = [&](int buf, int kv0) {
      unsigned short* Kbuf = lds + buf * 4096;
      unsigned short* Vbuf = lds + 8192 + buf * 4096;
      int r8 = lane >> 3;
      int colb = ((lane & 7) * 16) ^ (r8 << 4);
#pragma unroll
      for (int cc = 0; cc < 2; cc++) {
        int ch = w + cc * 4;
        const unsigned short* gk = Kb + (size_t)(kv0 + ch * 8 + r8) * 64 + (colb >> 1);
        __builtin_amdgcn_global_load_lds((const __attribute__((address_space(1))) void*)gk,
            (__attribute__((address_space(3))) void*)(Kbuf + ch * 512), 16, 0, 0);
        const unsigned short* gv = Vb + (size_t)(ch * 8 + r8) * Tt + kv0 + (colb >> 1);
        __builtin_amdgcn_global_load_lds((const __attribute__((address_space(1))) void*)gv,
            (__attribute__((address_space(3))) void*)(Vbuf + ch * 512), 16, 0, 0);
      }
    };

    short8 qf[4];
#pragma unroll
    for (int kk = 0; kk < 4; kk++)
      qf[kk] = *reinterpret_cast<const short8*>(Qb + (size_t)(qw0 + l31) * 64 + kk * 16 + hi * 8);

    float m_run = -1e30f, l_run = 0.f;
    f32x16 oacc[2] = {};

    stage(0, t0 * 64);
    __syncthreads();
    int cur = 0;
    for (int T = t0; T < t1; ++T) {
      if (T + 1 < t1) stage(cur ^ 1, (T + 1) * 64);
      attn_tile64(lds + cur * 4096, lds + 8192 + cur * 4096,
                  w, l31, hi, qf, m_run, l_run, oacc, 2 * T - 4 * qb);
      __syncthreads();
      cur ^= 1;
    }

    size_t orow = (size_t)sid * 128 + w * 32 + l31;
#pragma unroll
    for (int dt = 0; dt < 2; dt++)
#pragma unroll
      for (int q4 = 0; q4 < 4; q4++) {
        short4b oo;
#pragma unroll
        for (int jj = 0; jj < 4; jj++) oo[jj] = (short)f2b(oacc[dt][q4 * 4 + jj]);
        *reinterpret_cast<short4b*>(Opart + orow * 64 + dt * 32 + q4 * 8 + hi * 4) = oo;
      }
    if (hi == 0) {
      float2 v; v.x = m_run; v.y = l_run;
      *reinterpret_cast<float2*>(ml + orow * 2) = v;
    }
  }
}

// ------------- flash attention pass 2: merge the two KV chunks, normalize --------
__global__ __launch_bounds__(256)
void k_attn2(const unsigned short* __restrict__ Opart, const float* __restrict__ ml,
             unsigned short* __restrict__ Y) {
  int gid = blockIdx.x * 256 + threadIdx.x;
  int row = gid >> 3;
  int dblk = (gid & 7) * 8;
  int bh = row >> 11, q = row & 2047;
  int qb = q >> 7, qrow = q & 127;
  int s0 = (15 - qb) * 64 + bh;
  int s1 = s0 + 32;
  float2 ml0 = *reinterpret_cast<const float2*>(ml + ((size_t)s0 * 128 + qrow) * 2);
  float2 ml1 = *reinterpret_cast<const float2*>(ml + ((size_t)s1 * 128 + qrow) * 2);
  float m = fmaxf(ml0.x, ml1.x);
  float w0 = __builtin_amdgcn_exp2f(ml0.x - m);
  float w1 = __builtin_amdgcn_exp2f(ml1.x - m);
  float inv = 1.0f / (w0 * ml0.y + w1 * ml1.y);
  float a0 = w0 * inv, a1 = w1 * inv;
  short8 o0 = *reinterpret_cast<const short8*>(Opart + ((size_t)s0 * 128 + qrow) * 64 + dblk);
  short8 o1 = *reinterpret_cast<const short8*>(Opart + ((size_t)s1 * 128 + qrow) * 64 + dblk);
  short8 o;
#pragma unroll
  for (int j = 0; j < 8; j++) o[j] = (short)f2b(b2f(o0[j]) * a0 + b2f(o1[j]) * a1);
  int b = bh >> 4, h = bh & 15;
  *reinterpret_cast<short8*>(Y + ((size_t)(b * Tt + q)) * Cc + h * 64 + dblk) = o;
}

extern "C" void kernel_launch(void* const* d_in, const int* in_sizes, int n_in,
                              void* d_out, int out_size, void* d_ws, size_t ws_size,
                              hipStream_t stream) {
  (void)in_sizes; (void)n_in; (void)out_size; (void)ws_size;
  const float* x      = (const float*)d_in[0];
  const float* W_attn = (const float*)d_in[1];
  const float* b_attn = (const float*)d_in[2];
  const float* W_proj = (const float*)d_in[3];
  const float* b_proj = (const float*)d_in[4];
  const float* rope   = (const float*)d_in[5];
  float* out = (float*)d_out;

  char* ws = (char*)d_ws;
  unsigned short* xb    = (unsigned short*)(ws);                   // 8 MB
  unsigned short* WaT   = (unsigned short*)(ws + (8u << 20));      // 6 MB
  unsigned short* WpT   = (unsigned short*)(ws + (14u << 20));     // 2 MB
  unsigned short* Qs    = (unsigned short*)(ws + (16u << 20));     // 8 MB
  unsigned short* Ks    = (unsigned short*)(ws + (24u << 20));     // 8 MB
  unsigned short* Vt    = (unsigned short*)(ws + (32u << 20));     // 8 MB
  unsigned short* Yb    = (unsigned short*)(ws + (40u << 20));     // 8 MB
  unsigned short* Opart = (unsigned short*)(ws + (48u << 20));     // 16 MB
  float*          ml    = (float*)(ws + (64u << 20));              // 1 MB
  int*            ctr   = (int*)(ws + (65u << 20));                // 4 B

  constexpr int LDS_QKV  = (128 + 192) * 64 * 2 * 2;  // 81920 B  -> 2 blocks/CU
  constexpr int LDS_PROJ = (128 + 128) * 64 * 2 * 2;  // 65536 B
  (void)hipFuncSetAttribute(reinterpret_cast<const void*>(&k_gemm8<128, 3, 1>),
                            hipFuncAttributeMaxDynamicSharedMemorySize, LDS_QKV);
  (void)hipFuncSetAttribute(reinterpret_cast<const void*>(&k_gemm8<128, 2, 0>),
                            hipFuncAttributeMaxDynamicSharedMemorySize, LDS_PROJ);

  (void)hipMemsetAsync(ctr, 0, sizeof(int), stream);
  k_cast<<<2048, 256, 0, stream>>>(x, xb, BT * Cc);
  k_tcast<<<dim3(N1 / 32, Cc / 32), 256, 0, stream>>>(W_attn, WaT, Cc, N1);
  k_tcast<<<dim3(Cc / 32, Cc / 32), 256, 0, stream>>>(W_proj, WpT, Cc, Cc);
  k_gemm8<128, 3, 1><<<dim3(N1 / 192, BT / 128), 512, LDS_QKV, stream>>>(
      xb, WaT, b_attn, nullptr, rope, Qs, Ks, Vt, BT, N1, Cc);
  k_attn1<<<512, 256, 0, stream>>>(Qs, Ks, Vt, Opart, ml, ctr);
  k_attn2<<<2048, 256, 0, stream>>>(Opart, ml, Yb);
  k_gemm8<128, 2, 0><<<dim3(Cc / 128, BT / 128), 512, LDS_PROJ, stream>>>(
      Yb, WpT, b_proj, out, nullptr, nullptr, nullptr, nullptr, BT, Cc, Cc);
}

// Round 16
// 107.233 us; speedup vs baseline: 1.1736x; 1.1736x over previous
//
#include <hip/hip_runtime.h>
#include <hip/hip_bf16.h>

typedef __attribute__((ext_vector_type(8))) short short8;
typedef __attribute__((ext_vector_type(4))) short short4b;
typedef __attribute__((ext_vector_type(4))) float f32x4;
typedef __attribute__((ext_vector_type(16))) float f32x16;
typedef __attribute__((ext_vector_type(4))) unsigned u32x4;

static constexpr int Bb = 2, Tt = 2048, Cc = 1024, Hh = 16;
static constexpr int BT = Bb * Tt;     // 4096
static constexpr int N1 = 3 * Cc;      // 3072
static constexpr float QS = 0.125f * 1.44269504f;  // 1/sqrt(64) * log2(e)

__device__ __forceinline__ unsigned short f2b(float f) {
  union { float f; unsigned u; } v; v.f = f;
  unsigned r = v.u + 0x7fffu + ((v.u >> 16) & 1u);
  return (unsigned short)(r >> 16);
}
__device__ __forceinline__ float b2f(short s) {
  union { unsigned u; float f; } v; v.u = ((unsigned)(unsigned short)s) << 16;
  return v.f;
}

// ---------------- cast f32 -> bf16, 8 elems/thread ----------------
__global__ __launch_bounds__(256) void k_cast(const float* __restrict__ in,
                                              unsigned short* __restrict__ out, int n) {
  int i = (blockIdx.x * 256 + threadIdx.x) * 8;
  if (i >= n) return;
  float4 a = *reinterpret_cast<const float4*>(in + i);
  float4 b = *reinterpret_cast<const float4*>(in + i + 4);
  short8 o;
  o[0] = f2b(a.x); o[1] = f2b(a.y); o[2] = f2b(a.z); o[3] = f2b(a.w);
  o[4] = f2b(b.x); o[5] = f2b(b.y); o[6] = f2b(b.z); o[7] = f2b(b.w);
  *reinterpret_cast<short8*>(out + i) = o;
}

// ------------- transpose + cast: in R x Ccol f32 -> out Ccol x R bf16 -------------
__global__ __launch_bounds__(256) void k_tcast(const float* __restrict__ in,
                                               unsigned short* __restrict__ out,
                                               int R, int Ccol) {
  __shared__ float tile[32][33];
  int cb = blockIdx.x * 32, rb = blockIdx.y * 32;
  int tx = threadIdx.x & 31, ty = threadIdx.x >> 5;  // ty 0..7
  for (int i = 0; i < 32; i += 8)
    tile[ty + i][tx] = in[(size_t)(rb + ty + i) * Ccol + cb + tx];
  __syncthreads();
  for (int i = 0; i < 32; i += 8)
    out[(size_t)(cb + ty + i) * R + rb + tx] = f2b(tile[tx][ty + i]);
}

// ---------------- 8-wave phase-split GEMM (R11-proven) ----------------------------
template <int BM, int NF, int EPI>
__global__ __launch_bounds__(512, 2)
void k_gemm8(const unsigned short* __restrict__ A, const unsigned short* __restrict__ Bt,
             const float* __restrict__ bias, void* __restrict__ Cout,
             const float* __restrict__ rope, unsigned short* __restrict__ Qs,
             unsigned short* __restrict__ Ks, unsigned short* __restrict__ Vt,
             int M, int N, int K) {
  constexpr int BN = NF * 64;
  constexpr int MF = BM / 32;
  constexpr int AI = BM / 64;
  constexpr int ASZ = BM * 64;
  constexpr int BSZ = BN * 64;
  constexpr int STRIDE = ASZ + BSZ;
  extern __shared__ unsigned short lds[];
  const int tid = threadIdx.x, lane = tid & 63, w = tid >> 6;
  const int wm = w >> 2, wn = w & 3;
  const int l15 = lane & 15, l4 = lane >> 4;
  int nbx = gridDim.x;
  int lin = blockIdx.y * nbx + blockIdx.x;
  int cpx = (nbx * gridDim.y) >> 3;
  lin = (lin & 7) * cpx + (lin >> 3);
  const int mb = lin / nbx, nb = lin % nbx;
  const size_t arow0 = (size_t)mb * BM;
  const size_t brow0 = (size_t)nb * BN;

  const int srow = lane >> 3;
  const int scol = (((lane & 7) * 16) ^ (srow << 4)) >> 1;
  auto stage = [&](int buf, int k0) {
    unsigned short* Ab = lds + buf * STRIDE;
    unsigned short* Bb = Ab + ASZ;
#pragma unroll
    for (int i = 0; i < AI; i++) {
      int c = w + 8 * i;
      const unsigned short* g = A + (arow0 + c * 8 + srow) * (size_t)K + k0 + scol;
      __builtin_amdgcn_global_load_lds((const __attribute__((address_space(1))) void*)g,
          (__attribute__((address_space(3))) void*)(Ab + c * 512), 16, 0, 0);
    }
#pragma unroll
    for (int i = 0; i < NF; i++) {
      int c = w + 8 * i;
      const unsigned short* g = Bt + (brow0 + c * 8 + srow) * (size_t)K + k0 + scol;
      __builtin_amdgcn_global_load_lds((const __attribute__((address_space(1))) void*)g,
          (__attribute__((address_space(3))) void*)(Bb + c * 512), 16, 0, 0);
    }
  };

  f32x4 acc[MF][NF] = {};
  const int NK = K >> 6;

  stage(0, 0);
  asm volatile("s_waitcnt vmcnt(0)" ::: "memory");
  asm volatile("s_barrier" ::: "memory");

  for (int kt = 0; kt < NK; kt++) {
    int buf = kt & 1;
    if (kt + 1 < NK) stage(buf ^ 1, (kt + 1) << 6);
    const unsigned short* Ab = lds + buf * STRIDE;
    const unsigned short* Bb = Ab + ASZ;
    short8 af[MF][2];
#pragma unroll
    for (int p = 0; p < NF; p++) {
      if (p == 0) {
#pragma unroll
        for (int m = 0; m < MF; m++) {
          int ra = wm * (BM / 2) + m * 16 + l15;
#pragma unroll
          for (int kk = 0; kk < 2; kk++) {
            int cb = (kk * 64 + l4 * 16) ^ ((ra & 7) << 4);
            af[m][kk] = *reinterpret_cast<const short8*>(Ab + ra * 64 + (cb >> 1));
          }
        }
      }
      short8 bfr[2];
      int rb = wn * (NF * 16) + p * 16 + l15;
#pragma unroll
      for (int kk = 0; kk < 2; kk++) {
        int cb = (kk * 64 + l4 * 16) ^ ((rb & 7) << 4);
        bfr[kk] = *reinterpret_cast<const short8*>(Bb + rb * 64 + (cb >> 1));
      }
      asm volatile("s_barrier" ::: "memory");
      asm volatile("s_waitcnt lgkmcnt(0)" ::: "memory");
      __builtin_amdgcn_sched_barrier(0);
      __builtin_amdgcn_s_setprio(1);
#pragma unroll
      for (int m = 0; m < MF; m++) {
        acc[m][p] = __builtin_amdgcn_mfma_f32_16x16x32_bf16(af[m][0], bfr[0], acc[m][p], 0, 0, 0);
        acc[m][p] = __builtin_amdgcn_mfma_f32_16x16x32_bf16(af[m][1], bfr[1], acc[m][p], 0, 0, 0);
      }
      __builtin_amdgcn_s_setprio(0);
      if (p == NF - 1)
        asm volatile("s_waitcnt vmcnt(0)" ::: "memory");
      asm volatile("s_barrier" ::: "memory");
    }
  }

#pragma unroll
  for (int m = 0; m < MF; m++) {
#pragma unroll
    for (int n = 0; n < NF; n++) {
      int ccol0 = nb * BN + wn * (NF * 16) + n * 16;
      float bv = bias[ccol0 + l15];
      int r0 = mb * BM + wm * (BM / 2) + m * 16 + l4 * 4;
      if (EPI == 0) {
#pragma unroll
        for (int j = 0; j < 4; j++)
          ((float*)Cout)[(size_t)(r0 + j) * N + ccol0 + l15] = acc[m][n][j] + bv;
      } else {
        int cls = ccol0 >> 10;               // 0=q 1=k 2=v
        int h = (ccol0 >> 6) & 15;
        int d = (ccol0 & 63) + l15;
        int bq = r0 >> 11;
        int t0 = r0 & 2047;
        size_t bh = (size_t)bq * 16 + h;
        if (cls == 2) {
          short4b o;
#pragma unroll
          for (int j = 0; j < 4; j++) o[j] = (short)f2b(acc[m][n][j] + bv);
          *reinterpret_cast<short4b*>(Vt + (bh * 64 + d) * Tt + t0) = o;
        } else {
          unsigned short* dst = (cls == 0) ? Qs : Ks;
          int jj = d >> 1;
          int odd = d & 1;
#pragma unroll
          for (int j = 0; j < 4; j++) {
            float v = acc[m][n][j] + bv;
            float part = __shfl_xor(v, 1);
            float2 sc = *reinterpret_cast<const float2*>(
                rope + (size_t)(t0 + j) * 128 + jj * 4 + 2);   // (sin, cos)
            float x = odd ? part : v;
            float y = odd ? v : part;
            float rot = odd ? (x * sc.x + y * sc.y)
                            : (x * sc.y - y * sc.x);
            if (cls == 0) rot *= QS;
            dst[(bh * Tt + (t0 + j)) * 64 + d] = f2b(rot);
          }
        }
      }
    }
  }
}

__device__ __forceinline__ float tmax16(const f32x16& v) {
  float a0 = fmaxf(v[0], v[1]),   a1 = fmaxf(v[2], v[3]);
  float a2 = fmaxf(v[4], v[5]),   a3 = fmaxf(v[6], v[7]);
  float a4 = fmaxf(v[8], v[9]),   a5 = fmaxf(v[10], v[11]);
  float a6 = fmaxf(v[12], v[13]), a7 = fmaxf(v[14], v[15]);
  float b0 = fmaxf(a0, a1), b1 = fmaxf(a2, a3), b2 = fmaxf(a4, a5), b3 = fmaxf(a6, a7);
  return fmaxf(fmaxf(b0, b1), fmaxf(b2, b3));
}

// ------------- attention pass-1 tile (R11-proven) --------------------------------
__device__ __forceinline__ void attn_tile64(
    const unsigned short* Kl, const unsigned short* Vl,
    int w, int l31, int hi, const short8 qf[4],
    float& m_run, float& l_run, f32x16 oacc[2], int grelBase) {
  f32x16 sc[2];
  bool act[2];
#pragma unroll
  for (int kt = 0; kt < 2; kt++) {
    int grel = grelBase + kt;
    act[kt] = (grel <= w);
    if (!act[kt]) continue;
    f32x16 acc = {};
    int rk = kt * 32 + l31;
    int sw = (rk & 7) << 4;
    const unsigned short* krow = Kl + rk * 64;
    short8 kf[4];
#pragma unroll
    for (int kk = 0; kk < 4; kk++)
      kf[kk] = *reinterpret_cast<const short8*>(krow + (((kk * 32 + hi * 16) ^ sw) >> 1));
    __builtin_amdgcn_s_setprio(1);
#pragma unroll
    for (int kk = 0; kk < 4; kk++)
      acc = __builtin_amdgcn_mfma_f32_32x32x16_bf16(kf[kk], qf[kk], acc, 0, 0, 0);
    __builtin_amdgcn_s_setprio(0);
    if (grel == w) {
#pragma unroll
      for (int r = 0; r < 16; r++) {
        int e = (r & 3) + 8 * (r >> 2) + 4 * hi;
        if (e > l31) acc[r] = -1e30f;
      }
    }
    sc[kt] = acc;
  }
  float km0 = act[0] ? tmax16(sc[0]) : -1e30f;
  float km1 = act[1] ? tmax16(sc[1]) : -1e30f;
  float mx = fmaxf(km0, km1);
  mx = fmaxf(mx, __shfl_xor(mx, 32));

  float fsc = 1.f;
  if (!__all(mx <= m_run + 8.f)) {
    float nm = fmaxf(m_run, mx);
    fsc = __builtin_amdgcn_exp2f(m_run - nm);
    m_run = nm;
#pragma unroll
    for (int dt = 0; dt < 2; dt++)
#pragma unroll
      for (int r = 0; r < 16; r++) oacc[dt][r] *= fsc;
  }

  float kps[2] = {0.f, 0.f};
#pragma unroll
  for (int kt = 0; kt < 2; kt++) {
    if (!act[kt]) continue;
    float p[16];
#pragma unroll
    for (int r = 0; r < 16; r++) p[r] = __builtin_amdgcn_exp2f(sc[kt][r] - m_run);
    float s0 = (p[0] + p[1]) + (p[2] + p[3]);
    float s1 = (p[4] + p[5]) + (p[6] + p[7]);
    float s2 = (p[8] + p[9]) + (p[10] + p[11]);
    float s3 = (p[12] + p[13]) + (p[14] + p[15]);
    kps[kt] = (s0 + s1) + (s2 + s3);
    unsigned P[8];
#pragma unroll
    for (int i = 0; i < 8; i++)
      asm("v_cvt_pk_bf16_f32 %0, %1, %2" : "=v"(P[i]) : "v"(p[2 * i]), "v"(p[2 * i + 1]));
    unsigned Y0 = (unsigned)__shfl_xor((int)(hi ? P[0] : P[2]), 32);
    unsigned Y1 = (unsigned)__shfl_xor((int)(hi ? P[1] : P[3]), 32);
    unsigned Y2 = (unsigned)__shfl_xor((int)(hi ? P[4] : P[6]), 32);
    unsigned Y3 = (unsigned)__shfl_xor((int)(hi ? P[5] : P[7]), 32);
    u32x4 c0 = hi ? u32x4{Y0, Y1, P[2], P[3]} : u32x4{P[0], P[1], Y0, Y1};
    u32x4 c1 = hi ? u32x4{Y2, Y3, P[6], P[7]} : u32x4{P[4], P[5], Y2, Y3};
    short8 pf0 = __builtin_bit_cast(short8, c0);
    short8 pf1 = __builtin_bit_cast(short8, c1);
#pragma unroll
    for (int dt = 0; dt < 2; dt++) {
      int d = dt * 32 + l31;
      int sv = (d & 7) << 4;
      const unsigned short* vrow = Vl + d * 64;
      short8 vf0 = *reinterpret_cast<const short8*>(vrow + (((kt * 64 + hi * 16) ^ sv) >> 1));
      short8 vf1 = *reinterpret_cast<const short8*>(vrow + (((kt * 64 + 32 + hi * 16) ^ sv) >> 1));
      __builtin_amdgcn_s_setprio(1);
      oacc[dt] = __builtin_amdgcn_mfma_f32_32x32x16_bf16(vf0, pf0, oacc[dt], 0, 0, 0);
      oacc[dt] = __builtin_amdgcn_mfma_f32_32x32x16_bf16(vf1, pf1, oacc[dt], 0, 0, 0);
      __builtin_amdgcn_s_setprio(0);
    }
  }
  float psum = kps[0] + kps[1];
  psum += __shfl_xor(psum, 32);
  l_run = l_run * fsc + psum;
}

// ------------- flash attention pass 1: split-KV, 64-key tiles, 32KB LDS (R11) ----
__global__ __launch_bounds__(256)
void k_attn1(const unsigned short* __restrict__ Qs, const unsigned short* __restrict__ Ks,
             const unsigned short* __restrict__ Vt, unsigned short* __restrict__ Opart,
             float* __restrict__ ml) {
  __shared__ unsigned short lds[16384];
  int tid = threadIdx.x, lane = tid & 63, w = tid >> 6;
  int sid = blockIdx.x;                // 0..1023
  int qb = 15 - (sid >> 6);
  int c = (sid >> 5) & 1;
  int bh = sid & 31;
  int l31 = lane & 31, hi = lane >> 5;
  int qw0 = qb * 128 + w * 32;
  const unsigned short* Qb = Qs + (size_t)bh * Tt * 64;
  const unsigned short* Kb = Ks + (size_t)bh * Tt * 64;
  const unsigned short* Vb = Vt + (size_t)bh * 64 * Tt;

  const int NT = 2 * qb + 2;
  const int half = NT >> 1;
  const int t0 = c ? half : 0;
  const int t1 = c ? NT : half;

  auto stage = [&](int buf, int kv0) {
    unsigned short* Kbuf = lds + buf * 4096;
    unsigned short* Vbuf = lds + 8192 + buf * 4096;
    int r8 = lane >> 3;
    int colb = ((lane & 7) * 16) ^ (r8 << 4);
#pragma unroll
    for (int cc = 0; cc < 2; cc++) {
      int ch = w + cc * 4;
      const unsigned short* gk = Kb + (size_t)(kv0 + ch * 8 + r8) * 64 + (colb >> 1);
      __builtin_amdgcn_global_load_lds((const __attribute__((address_space(1))) void*)gk,
          (__attribute__((address_space(3))) void*)(Kbuf + ch * 512), 16, 0, 0);
      const unsigned short* gv = Vb + (size_t)(ch * 8 + r8) * Tt + kv0 + (colb >> 1);
      __builtin_amdgcn_global_load_lds((const __attribute__((address_space(1))) void*)gv,
          (__attribute__((address_space(3))) void*)(Vbuf + ch * 512), 16, 0, 0);
    }
  };

  short8 qf[4];
#pragma unroll
  for (int kk = 0; kk < 4; kk++)
    qf[kk] = *reinterpret_cast<const short8*>(Qb + (size_t)(qw0 + l31) * 64 + kk * 16 + hi * 8);

  float m_run = -1e30f, l_run = 0.f;
  f32x16 oacc[2] = {};

  stage(0, t0 * 64);
  __syncthreads();
  int cur = 0;
  for (int T = t0; T < t1; ++T) {
    if (T + 1 < t1) stage(cur ^ 1, (T + 1) * 64);
    attn_tile64(lds + cur * 4096, lds + 8192 + cur * 4096,
                w, l31, hi, qf, m_run, l_run, oacc, 2 * T - 4 * qb);
    __syncthreads();
    cur ^= 1;
  }

  size_t orow = (size_t)sid * 128 + w * 32 + l31;
#pragma unroll
  for (int dt = 0; dt < 2; dt++)
#pragma unroll
    for (int q4 = 0; q4 < 4; q4++) {
      short4b oo;
#pragma unroll
      for (int jj = 0; jj < 4; jj++) oo[jj] = (short)f2b(oacc[dt][q4 * 4 + jj]);
      *reinterpret_cast<short4b*>(Opart + orow * 64 + dt * 32 + q4 * 8 + hi * 4) = oo;
    }
  if (hi == 0) {
    float2 v; v.x = m_run; v.y = l_run;
    *reinterpret_cast<float2*>(ml + orow * 2) = v;
  }
}

// ------------- flash attention pass 2: merge the two KV chunks, normalize --------
__global__ __launch_bounds__(256)
void k_attn2(const unsigned short* __restrict__ Opart, const float* __restrict__ ml,
             unsigned short* __restrict__ Y) {
  int gid = blockIdx.x * 256 + threadIdx.x;
  int row = gid >> 3;
  int dblk = (gid & 7) * 8;
  int bh = row >> 11, q = row & 2047;
  int qb = q >> 7, qrow = q & 127;
  int s0 = (15 - qb) * 64 + bh;
  int s1 = s0 + 32;
  float2 ml0 = *reinterpret_cast<const float2*>(ml + ((size_t)s0 * 128 + qrow) * 2);
  float2 ml1 = *reinterpret_cast<const float2*>(ml + ((size_t)s1 * 128 + qrow) * 2);
  float m = fmaxf(ml0.x, ml1.x);
  float w0 = __builtin_amdgcn_exp2f(ml0.x - m);
  float w1 = __builtin_amdgcn_exp2f(ml1.x - m);
  float inv = 1.0f / (w0 * ml0.y + w1 * ml1.y);
  float a0 = w0 * inv, a1 = w1 * inv;
  short8 o0 = *reinterpret_cast<const short8*>(Opart + ((size_t)s0 * 128 + qrow) * 64 + dblk);
  short8 o1 = *reinterpret_cast<const short8*>(Opart + ((size_t)s1 * 128 + qrow) * 64 + dblk);
  short8 o;
#pragma unroll
  for (int j = 0; j < 8; j++) o[j] = (short)f2b(b2f(o0[j]) * a0 + b2f(o1[j]) * a1);
  int b = bh >> 4, h = bh & 15;
  *reinterpret_cast<short8*>(Y + ((size_t)(b * Tt + q)) * Cc + h * 64 + dblk) = o;
}

extern "C" void kernel_launch(void* const* d_in, const int* in_sizes, int n_in,
                              void* d_out, int out_size, void* d_ws, size_t ws_size,
                              hipStream_t stream) {
  (void)in_sizes; (void)n_in; (void)out_size; (void)ws_size;
  const float* x      = (const float*)d_in[0];
  const float* W_attn = (const float*)d_in[1];
  const float* b_attn = (const float*)d_in[2];
  const float* W_proj = (const float*)d_in[3];
  const float* b_proj = (const float*)d_in[4];
  const float* rope   = (const float*)d_in[5];
  float* out = (float*)d_out;

  char* ws = (char*)d_ws;
  unsigned short* xb    = (unsigned short*)(ws);                   // 8 MB
  unsigned short* WaT   = (unsigned short*)(ws + (8u << 20));      // 6 MB
  unsigned short* WpT   = (unsigned short*)(ws + (14u << 20));     // 2 MB
  unsigned short* Qs    = (unsigned short*)(ws + (16u << 20));     // 8 MB
  unsigned short* Ks    = (unsigned short*)(ws + (24u << 20));     // 8 MB
  unsigned short* Vt    = (unsigned short*)(ws + (32u << 20));     // 8 MB
  unsigned short* Yb    = (unsigned short*)(ws + (40u << 20));     // 8 MB
  unsigned short* Opart = (unsigned short*)(ws + (48u << 20));     // 16 MB
  float*          ml    = (float*)(ws + (64u << 20));              // 1 MB

  constexpr int LDS_QKV  = (128 + 192) * 64 * 2 * 2;  // 81920 B  -> 2 blocks/CU
  constexpr int LDS_PROJ = (128 + 128) * 64 * 2 * 2;  // 65536 B
  (void)hipFuncSetAttribute(reinterpret_cast<const void*>(&k_gemm8<128, 3, 1>),
                            hipFuncAttributeMaxDynamicSharedMemorySize, LDS_QKV);
  (void)hipFuncSetAttribute(reinterpret_cast<const void*>(&k_gemm8<128, 2, 0>),
                            hipFuncAttributeMaxDynamicSharedMemorySize, LDS_PROJ);

  k_cast<<<2048, 256, 0, stream>>>(x, xb, BT * Cc);
  k_tcast<<<dim3(N1 / 32, Cc / 32), 256, 0, stream>>>(W_attn, WaT, Cc, N1);
  k_tcast<<<dim3(Cc / 32, Cc / 32), 256, 0, stream>>>(W_proj, WpT, Cc, Cc);
  k_gemm8<128, 3, 1><<<dim3(N1 / 192, BT / 128), 512, LDS_QKV, stream>>>(
      xb, WaT, b_attn, nullptr, rope, Qs, Ks, Vt, BT, N1, Cc);
  k_attn1<<<1024, 256, 0, stream>>>(Qs, Ks, Vt, Opart, ml);
  k_attn2<<<2048, 256, 0, stream>>>(Opart, ml, Yb);
  k_gemm8<128, 2, 0><<<dim3(Cc / 128, BT / 128), 512, LDS_PROJ, stream>>>(
      Yb, WpT, b_proj, out, nullptr, nullptr, nullptr, nullptr, BT, Cc, Cc);
}